// Round 4
// baseline (313.588 us; speedup 1.0000x reference)
//
#include <hip/hip_runtime.h>
#include <math.h>

#define BB 2
#define CC 192
#define NH 4
#define CH 48
#define SRCP 16
#define HH 256
#define WW 256
#define NPIX (HH*WW)

typedef __attribute__((ext_vector_type(8))) short short8;   // 8 bf16 = 4 VGPR
typedef __attribute__((ext_vector_type(4))) float f4;

static __device__ __forceinline__ unsigned short f2bf(float f) {
    union { float f; unsigned int u; } c; c.f = f;
    unsigned int r = c.u + 0x7fffu + ((c.u >> 16) & 1u);
    return (unsigned short)(r >> 16);
}

// K1: depthwise 3x3 conv for one (b, head, row). q,k -> LDS bf16 rows [c][256]
// (132-dword stride). v -> global ws [n][dg] bf16. Then sumsq(q,k) and
// S += q k^T via MFMA 16x16x32 bf16, accumulated to global S with atomics.
// Loads batched 4 channel-groups at a time (36 loads in flight) for MLP.
__global__ __launch_bounds__(256, 3) void k_conv(
    const float* __restrict__ x, const float* __restrict__ wqkv,
    unsigned short* __restrict__ vws, float* __restrict__ Sws,
    float* __restrict__ sqws)
{
    __shared__ unsigned int qk32[2][CH][132]; // 50688 B -> 3 blocks/CU

    const int tid = threadIdx.x;
    const int hd = blockIdx.x;
    const int y  = blockIdx.y;
    const int b  = blockIdx.z;

    {
        const int xp = tid;
        const int y0 = (y > 0) ? (y-1) : 0;
        const int y2 = (y < HH-1) ? (y+1) : y;
        const int xl = (xp > 0) ? (xp-1) : 0;
        const int xr = (xp < WW-1) ? (xp+1) : xp;
        const float my0 = (y > 0) ? 1.f : 0.f;
        const float my2 = (y < HH-1) ? 1.f : 0.f;
        const float mx0 = (xp > 0) ? 1.f : 0.f;
        const float mx2 = (xp < WW-1) ? 1.f : 0.f;
        const float m00 = my0*mx0, m02 = my0*mx2, m20 = my2*mx0, m22 = my2*mx2;

        // types 0 (q) and 1 (k) -> LDS; loads batched 4 groups at a time
        #pragma unroll
        for (int type = 0; type < 2; ++type) {
            const int srcbase = type*64 + SRCP*hd;
            const float* wt = wqkv + type*(CC*9) + hd*(CH*9);   // uniform -> s_load
            for (int g4 = 0; g4 < SRCP; g4 += 4) {
                float A[4][9];
                #pragma unroll
                for (int u = 0; u < 4; ++u) {
                    const float* base = x + ((size_t)(b*CC + srcbase + g4 + u)*HH)*WW;
                    const float* r0 = base + (size_t)y0*WW;
                    const float* r1 = base + (size_t)y *WW;
                    const float* r2 = base + (size_t)y2*WW;
                    A[u][0] = r0[xl]; A[u][1] = r0[xp]; A[u][2] = r0[xr];
                    A[u][3] = r1[xl]; A[u][4] = r1[xp]; A[u][5] = r1[xr];
                    A[u][6] = r2[xl]; A[u][7] = r2[xp]; A[u][8] = r2[xr];
                }
                #pragma unroll
                for (int u = 0; u < 4; ++u) {
                    const int g = g4 + u;
                    float a00 = A[u][0]*m00, a01 = A[u][1]*my0, a02 = A[u][2]*m02;
                    float a10 = A[u][3]*mx0, a11 = A[u][4],     a12 = A[u][5]*mx2;
                    float a20 = A[u][6]*m20, a21 = A[u][7]*my2, a22 = A[u][8]*m22;
                    #pragma unroll
                    for (int r = 0; r < 3; ++r) {
                        const int cl = 3*g + r;
                        const float* w = wt + cl*9;
                        float val = a00*w[0] + a01*w[1] + a02*w[2]
                                  + a10*w[3] + a11*w[4] + a12*w[5]
                                  + a20*w[6] + a21*w[7] + a22*w[8];
                        ((unsigned short*)&qk32[type][cl][0])[xp] = f2bf(val);
                    }
                }
            }
        }

        // type 2 (v): batched loads, fully unrolled so vpack[] stays in registers
        unsigned int vpack[24];
        {
            const int srcbase = 128 + SRCP*hd;
            const float* wt = wqkv + 2*(CC*9) + hd*(CH*9);      // uniform -> s_load
            #pragma unroll
            for (int g4 = 0; g4 < SRCP; g4 += 4) {
                float A[4][9];
                #pragma unroll
                for (int u = 0; u < 4; ++u) {
                    const float* base = x + ((size_t)(b*CC + srcbase + g4 + u)*HH)*WW;
                    const float* r0 = base + (size_t)y0*WW;
                    const float* r1 = base + (size_t)y *WW;
                    const float* r2 = base + (size_t)y2*WW;
                    A[u][0] = r0[xl]; A[u][1] = r0[xp]; A[u][2] = r0[xr];
                    A[u][3] = r1[xl]; A[u][4] = r1[xp]; A[u][5] = r1[xr];
                    A[u][6] = r2[xl]; A[u][7] = r2[xp]; A[u][8] = r2[xr];
                }
                #pragma unroll
                for (int u = 0; u < 4; ++u) {
                    const int g = g4 + u;
                    float a00 = A[u][0]*m00, a01 = A[u][1]*my0, a02 = A[u][2]*m02;
                    float a10 = A[u][3]*mx0, a11 = A[u][4],     a12 = A[u][5]*mx2;
                    float a20 = A[u][6]*m20, a21 = A[u][7]*my2, a22 = A[u][8]*m22;
                    #pragma unroll
                    for (int r = 0; r < 3; ++r) {
                        const int cl = 3*g + r;
                        const float* w = wt + cl*9;
                        float val = a00*w[0] + a01*w[1] + a02*w[2]
                                  + a10*w[3] + a11*w[4] + a12*w[5]
                                  + a20*w[6] + a21*w[7] + a22*w[8];
                        unsigned int uu = f2bf(val);
                        if (cl & 1) vpack[cl >> 1] |= (uu << 16);
                        else        vpack[cl >> 1]  = uu;
                    }
                }
            }
        }
        // write v: [b][n][dg] layout, 6 x dwordx4 (16B each, 384B row stride)
        {
            unsigned short* vp = vws + ((size_t)b*NPIX + (size_t)y*WW + xp)*CC + hd*CH;
            #pragma unroll
            for (int st = 0; st < 6; ++st) {
                uint4 u; u.x = vpack[st*4+0]; u.y = vpack[st*4+1];
                         u.z = vpack[st*4+2]; u.w = vpack[st*4+3];
                *(uint4*)(vp + st*8) = u;
            }
        }
    }
    __syncthreads();

    // per-channel sum of squares for q,k norms
    if (tid < 2*CH) {
        const int which = tid / CH;
        const int cl = tid - which*CH;
        const uint4* row = (const uint4*)&qk32[which][cl][0];
        float ssum = 0.f;
        for (int j = 0; j < 32; ++j) {
            uint4 u = row[j];
            #pragma unroll
            for (int q4 = 0; q4 < 4; ++q4) {
                unsigned int w = (&u.x)[q4];
                float lo = __uint_as_float(w << 16);
                float hi = __uint_as_float(w & 0xffff0000u);
                ssum = fmaf(lo, lo, ssum);
                ssum = fmaf(hi, hi, ssum);
            }
        }
        atomicAdd(&sqws[((b*NH + hd)*2 + which)*CH + cl], ssum);
    }

    // S = q k^T via MFMA: A[m=c][k=n], B[k=n][nn=d]; both frags read 8
    // consecutive bf16 from a channel row at n = ks*32 + quad*8.
    {
        const int lane = tid & 63;
        const int wv = tid >> 6;
        const int m = lane & 15, quad = lane >> 4;
        for (int p = wv; p < 9; p += 4) {
            const int ct = p / 3, dt = p - ct*3;
            f4 acc = {0.f, 0.f, 0.f, 0.f};
            const char* qbase = (const char*)&qk32[0][ct*16 + m][0] + quad*16;
            const char* kbase = (const char*)&qk32[1][dt*16 + m][0] + quad*16;
            #pragma unroll
            for (int ks = 0; ks < 8; ++ks) {
                short8 afr = *(const short8*)(qbase + ks*64);
                short8 bfr = *(const short8*)(kbase + ks*64);
                acc = __builtin_amdgcn_mfma_f32_16x16x32_bf16(afr, bfr, acc, 0, 0, 0);
            }
            const int c0 = ct*16 + quad*4, d = dt*16 + m;
            float* Sp = Sws + ((size_t)(b*NH + hd)*CH + c0)*CH + d;
            #pragma unroll
            for (int r = 0; r < 4; ++r) atomicAdd(Sp + r*CH, acc[r]);
        }
    }
}

// K2: one block per (b,head): norms -> logits -> softmax -> W2 = wproj*attn,
// exported bf16 in [o][dg] (A-operand-ready) layout.
__global__ __launch_bounds__(256) void k_attn(
    const float* __restrict__ Sws, const float* __restrict__ sqws,
    const float* __restrict__ temp, const float* __restrict__ wproj,
    unsigned short* __restrict__ W2bf)
{
    __shared__ float att[CH][CH+1];
    __shared__ float wp[CC][CH+1];
    __shared__ float nrm[2][CH];

    const int tid = threadIdx.x;
    const int b  = blockIdx.x >> 2;
    const int hd = blockIdx.x & 3;

    if (tid < 2*CH) {
        int which = tid / CH, cl = tid - which*CH;
        nrm[which][cl] = fmaxf(sqrtf(sqws[((b*NH + hd)*2 + which)*CH + cl]), 1e-12f);
    }
    __syncthreads();

    const float tscale = temp[hd];
    for (int m = tid; m < CH*CH; m += 256) {
        int c = m / CH, d = m - c*CH;
        att[c][d] = Sws[((size_t)(b*NH + hd)*CH + c)*CH + d] * tscale
                    / (nrm[0][c] * nrm[1][d]);
    }
    __syncthreads();

    if (tid < CH) {
        float mx = -1e30f;
        for (int d = 0; d < CH; ++d) mx = fmaxf(mx, att[tid][d]);
        float sm = 0.f;
        for (int d = 0; d < CH; ++d) { float e = expf(att[tid][d] - mx); att[tid][d] = e; sm += e; }
        float inv = 1.f / sm;
        for (int d = 0; d < CH; ++d) att[tid][d] *= inv;
    }

    for (int m = tid; m < CC*CH; m += 256) {
        int o = m / CH, il = m - o*CH;
        wp[o][il] = wproj[o*CC + hd*CH + il];
    }
    __syncthreads();

    const int o0  = (tid & 31) * 6;
    const int dl0 = (tid >> 5) * 6;
    float a[6][6];
    #pragma unroll
    for (int i = 0; i < 6; ++i)
        #pragma unroll
        for (int j = 0; j < 6; ++j) a[i][j] = 0.f;
    for (int il = 0; il < CH; ++il) {
        float wv[6], av[6];
        #pragma unroll
        for (int i = 0; i < 6; ++i) wv[i] = wp[o0+i][il];
        #pragma unroll
        for (int j = 0; j < 6; ++j) av[j] = att[il][dl0+j];
        #pragma unroll
        for (int i = 0; i < 6; ++i)
            #pragma unroll
            for (int j = 0; j < 6; ++j)
                a[i][j] = fmaf(wv[i], av[j], a[i][j]);
    }
    #pragma unroll
    for (int i = 0; i < 6; ++i)
        #pragma unroll
        for (int j = 0; j < 6; ++j)
            W2bf[((size_t)b*CC + o0 + i)*CC + hd*CH + dl0 + j] = f2bf(a[i][j]);
}

// K3: out[b][o][n] = sum_dg W2[o][dg] v[n][dg]  — MFMA GEMM.
// Block: M=192 x N=128, 4 waves in 2x2 (M-half x N-half). A from LDS-staged
// bf16 W2 (restored: round-3 global-A regressed -14us), B straight from
// global v. Epilogue: acc transposed through LDS (reusing w2l, per-wave
// regions, 2 phases of 3 m-tiles) -> dwordx4 stores (96 scalar -> 24 vector).
__global__ __launch_bounds__(256, 2) void k_out(
    const unsigned short* __restrict__ vws, const unsigned short* __restrict__ W2bf,
    float* __restrict__ out)
{
    __shared__ unsigned short w2l[CC][200];   // 76800 B; stride 400B: aligned, 2-way banks

    const int tid = threadIdx.x;
    const int b  = blockIdx.y;
    const int n0 = blockIdx.x * 128;

    {
        const uint4* src = (const uint4*)(W2bf + (size_t)b*CC*CC);
        for (int i = tid; i < CC*24; i += 256) {
            int o = i / 24, c = i - o*24;
            *(uint4*)&w2l[o][c*8] = src[i];
        }
    }
    __syncthreads();

    const int lane = tid & 63;
    const int wv = tid >> 6;
    const int m0  = (wv & 1) * 96;
    const int nn0 = (wv >> 1) * 64;
    const int m = lane & 15, quad = lane >> 4;

    f4 acc[6][4];
    #pragma unroll
    for (int mt = 0; mt < 6; ++mt)
        #pragma unroll
        for (int nt = 0; nt < 4; ++nt) acc[mt][nt] = (f4){0.f, 0.f, 0.f, 0.f};

    const unsigned short* vb = vws + ((size_t)b*NPIX + n0 + nn0 + m)*CC + quad*8;

    #pragma unroll
    for (int ks = 0; ks < 6; ++ks) {
        short8 bfr[4];
        #pragma unroll
        for (int nt = 0; nt < 4; ++nt)
            bfr[nt] = *(const short8*)(vb + (size_t)(nt*16)*CC + ks*32);
        short8 afr[6];
        #pragma unroll
        for (int mt = 0; mt < 6; ++mt)
            afr[mt] = *(const short8*)&w2l[m0 + mt*16 + m][ks*32 + quad*8];
        #pragma unroll
        for (int mt = 0; mt < 6; ++mt)
            #pragma unroll
            for (int nt = 0; nt < 4; ++nt)
                acc[mt][nt] = __builtin_amdgcn_mfma_f32_16x16x32_bf16(afr[mt], bfr[nt], acc[mt][nt], 0, 0, 0);
    }

    // ---- epilogue: per-wave LDS transpose (reuse w2l) -> dwordx4 stores.
    // trsp layout: [wave][mtloc 0..2][o_local 16][px 68] f32 = 52224 B < 76800.
    float* trsp = (float*)w2l;
    const int orow = lane >> 2;          // 0..15
    const int seg  = (lane & 3) * 16;    // 0,16,32,48

    #pragma unroll
    for (int ph = 0; ph < 2; ++ph) {
        const int mtb = ph * 3;
        __syncthreads();                 // w2l reads (GEMM / prev phase) done
        #pragma unroll
        for (int mtl = 0; mtl < 3; ++mtl)
            #pragma unroll
            for (int nt = 0; nt < 4; ++nt)
                #pragma unroll
                for (int r = 0; r < 4; ++r)
                    trsp[((wv*3 + mtl)*16 + quad*4 + r)*68 + nt*16 + m] = acc[mtb+mtl][nt][r];
        __syncthreads();
        #pragma unroll
        for (int mtl = 0; mtl < 3; ++mtl) {
            const float* srcp = &trsp[((wv*3 + mtl)*16 + orow)*68 + seg];
            f4 d0 = *(const f4*)(srcp + 0);
            f4 d1 = *(const f4*)(srcp + 4);
            f4 d2 = *(const f4*)(srcp + 8);
            f4 d3 = *(const f4*)(srcp + 12);
            const int o = m0 + (mtb + mtl)*16 + orow;
            float* op = out + ((size_t)(b*CC + o))*NPIX + n0 + nn0 + seg;
            *(f4*)(op + 0)  = d0;
            *(f4*)(op + 4)  = d1;
            *(f4*)(op + 8)  = d2;
            *(f4*)(op + 12) = d3;
        }
    }
}

extern "C" void kernel_launch(void* const* d_in, const int* in_sizes, int n_in,
                              void* d_out, int out_size, void* d_ws, size_t ws_size,
                              hipStream_t stream)
{
    const float* x     = (const float*)d_in[0];
    const float* wqkv  = (const float*)d_in[1];
    const float* temp  = (const float*)d_in[2];
    const float* wproj = (const float*)d_in[3];
    float* out = (float*)d_out;
    (void)in_sizes; (void)n_in; (void)out_size; (void)ws_size;

    unsigned short* vws = (unsigned short*)d_ws;                 // [b][n][dg] bf16: 50,331,648 B
    const size_t VBYTES = (size_t)BB*CC*NPIX*sizeof(unsigned short);
    float* Sws  = (float*)((char*)d_ws + VBYTES);                // 18432 f
    float* sqws = Sws + (size_t)BB*NH*CH*CH;                     // 768 f
    unsigned short* W2bf = (unsigned short*)(sqws + (size_t)BB*NH*2*CH); // 73728 u16

    hipMemsetAsync(Sws, 0, (size_t)(BB*NH*CH*CH + BB*NH*2*CH)*sizeof(float), stream);
    k_conv<<<dim3(NH, HH, BB), 256, 0, stream>>>(x, wqkv, vws, Sws, sqws);
    k_attn<<<dim3(BB*NH), 256, 0, stream>>>(Sws, sqws, temp, wproj, W2bf);
    k_out<<<dim3(NPIX/128, BB), 256, 0, stream>>>(vws, W2bf, out);
}

// Round 5
// 298.917 us; speedup vs baseline: 1.0491x; 1.0491x over previous
//
#include <hip/hip_runtime.h>
#include <math.h>

#define BB 2
#define CC 192
#define NH 4
#define CH 48
#define SRCP 16
#define HH 256
#define WW 256
#define NPIX (HH*WW)

typedef __attribute__((ext_vector_type(8))) short short8;   // 8 bf16 = 4 VGPR
typedef __attribute__((ext_vector_type(4))) float f4;

static __device__ __forceinline__ unsigned short f2bf(float f) {
    union { float f; unsigned int u; } c; c.f = f;
    unsigned int r = c.u + 0x7fffu + ((c.u >> 16) & 1u);
    return (unsigned short)(r >> 16);
}

// K1: depthwise 3x3 conv for one (b, head, row). q,k -> LDS bf16 rows [c][256]
// (132-dword stride). v -> global ws [n][dg] bf16. Then sumsq(q,k) and
// S += q k^T via MFMA 16x16x32 bf16, accumulated to global S with atomics.
// Loads batched 4 channel-groups at a time (36 loads in flight) for MLP.
__global__ __launch_bounds__(256, 3) void k_conv(
    const float* __restrict__ x, const float* __restrict__ wqkv,
    unsigned short* __restrict__ vws, float* __restrict__ Sws,
    float* __restrict__ sqws)
{
    __shared__ unsigned int qk32[2][CH][132]; // 50688 B -> 3 blocks/CU

    const int tid = threadIdx.x;
    const int hd = blockIdx.x;
    const int y  = blockIdx.y;
    const int b  = blockIdx.z;

    {
        const int xp = tid;
        const int y0 = (y > 0) ? (y-1) : 0;
        const int y2 = (y < HH-1) ? (y+1) : y;
        const int xl = (xp > 0) ? (xp-1) : 0;
        const int xr = (xp < WW-1) ? (xp+1) : xp;
        const float my0 = (y > 0) ? 1.f : 0.f;
        const float my2 = (y < HH-1) ? 1.f : 0.f;
        const float mx0 = (xp > 0) ? 1.f : 0.f;
        const float mx2 = (xp < WW-1) ? 1.f : 0.f;
        const float m00 = my0*mx0, m02 = my0*mx2, m20 = my2*mx0, m22 = my2*mx2;

        // types 0 (q) and 1 (k) -> LDS; loads batched 4 groups at a time
        #pragma unroll
        for (int type = 0; type < 2; ++type) {
            const int srcbase = type*64 + SRCP*hd;
            const float* wt = wqkv + type*(CC*9) + hd*(CH*9);   // uniform -> s_load
            for (int g4 = 0; g4 < SRCP; g4 += 4) {
                float A[4][9];
                #pragma unroll
                for (int u = 0; u < 4; ++u) {
                    const float* base = x + ((size_t)(b*CC + srcbase + g4 + u)*HH)*WW;
                    const float* r0 = base + (size_t)y0*WW;
                    const float* r1 = base + (size_t)y *WW;
                    const float* r2 = base + (size_t)y2*WW;
                    A[u][0] = r0[xl]; A[u][1] = r0[xp]; A[u][2] = r0[xr];
                    A[u][3] = r1[xl]; A[u][4] = r1[xp]; A[u][5] = r1[xr];
                    A[u][6] = r2[xl]; A[u][7] = r2[xp]; A[u][8] = r2[xr];
                }
                #pragma unroll
                for (int u = 0; u < 4; ++u) {
                    const int g = g4 + u;
                    float a00 = A[u][0]*m00, a01 = A[u][1]*my0, a02 = A[u][2]*m02;
                    float a10 = A[u][3]*mx0, a11 = A[u][4],     a12 = A[u][5]*mx2;
                    float a20 = A[u][6]*m20, a21 = A[u][7]*my2, a22 = A[u][8]*m22;
                    #pragma unroll
                    for (int r = 0; r < 3; ++r) {
                        const int cl = 3*g + r;
                        const float* w = wt + cl*9;
                        float val = a00*w[0] + a01*w[1] + a02*w[2]
                                  + a10*w[3] + a11*w[4] + a12*w[5]
                                  + a20*w[6] + a21*w[7] + a22*w[8];
                        ((unsigned short*)&qk32[type][cl][0])[xp] = f2bf(val);
                    }
                }
            }
        }

        // type 2 (v): batched loads, fully unrolled so vpack[] stays in registers
        unsigned int vpack[24];
        {
            const int srcbase = 128 + SRCP*hd;
            const float* wt = wqkv + 2*(CC*9) + hd*(CH*9);      // uniform -> s_load
            #pragma unroll
            for (int g4 = 0; g4 < SRCP; g4 += 4) {
                float A[4][9];
                #pragma unroll
                for (int u = 0; u < 4; ++u) {
                    const float* base = x + ((size_t)(b*CC + srcbase + g4 + u)*HH)*WW;
                    const float* r0 = base + (size_t)y0*WW;
                    const float* r1 = base + (size_t)y *WW;
                    const float* r2 = base + (size_t)y2*WW;
                    A[u][0] = r0[xl]; A[u][1] = r0[xp]; A[u][2] = r0[xr];
                    A[u][3] = r1[xl]; A[u][4] = r1[xp]; A[u][5] = r1[xr];
                    A[u][6] = r2[xl]; A[u][7] = r2[xp]; A[u][8] = r2[xr];
                }
                #pragma unroll
                for (int u = 0; u < 4; ++u) {
                    const int g = g4 + u;
                    float a00 = A[u][0]*m00, a01 = A[u][1]*my0, a02 = A[u][2]*m02;
                    float a10 = A[u][3]*mx0, a11 = A[u][4],     a12 = A[u][5]*mx2;
                    float a20 = A[u][6]*m20, a21 = A[u][7]*my2, a22 = A[u][8]*m22;
                    #pragma unroll
                    for (int r = 0; r < 3; ++r) {
                        const int cl = 3*g + r;
                        const float* w = wt + cl*9;
                        float val = a00*w[0] + a01*w[1] + a02*w[2]
                                  + a10*w[3] + a11*w[4] + a12*w[5]
                                  + a20*w[6] + a21*w[7] + a22*w[8];
                        unsigned int uu = f2bf(val);
                        if (cl & 1) vpack[cl >> 1] |= (uu << 16);
                        else        vpack[cl >> 1]  = uu;
                    }
                }
            }
        }
        // write v: [b][n][dg] layout, 6 x dwordx4 (16B each, 384B row stride)
        {
            unsigned short* vp = vws + ((size_t)b*NPIX + (size_t)y*WW + xp)*CC + hd*CH;
            #pragma unroll
            for (int st = 0; st < 6; ++st) {
                uint4 u; u.x = vpack[st*4+0]; u.y = vpack[st*4+1];
                         u.z = vpack[st*4+2]; u.w = vpack[st*4+3];
                *(uint4*)(vp + st*8) = u;
            }
        }
    }
    __syncthreads();

    // per-channel sum of squares for q,k norms
    if (tid < 2*CH) {
        const int which = tid / CH;
        const int cl = tid - which*CH;
        const uint4* row = (const uint4*)&qk32[which][cl][0];
        float ssum = 0.f;
        for (int j = 0; j < 32; ++j) {
            uint4 u = row[j];
            #pragma unroll
            for (int q4 = 0; q4 < 4; ++q4) {
                unsigned int w = (&u.x)[q4];
                float lo = __uint_as_float(w << 16);
                float hi = __uint_as_float(w & 0xffff0000u);
                ssum = fmaf(lo, lo, ssum);
                ssum = fmaf(hi, hi, ssum);
            }
        }
        atomicAdd(&sqws[((b*NH + hd)*2 + which)*CH + cl], ssum);
    }

    // S = q k^T via MFMA: A[m=c][k=n], B[k=n][nn=d]; both frags read 8
    // consecutive bf16 from a channel row at n = ks*32 + quad*8.
    {
        const int lane = tid & 63;
        const int wv = tid >> 6;
        const int m = lane & 15, quad = lane >> 4;
        for (int p = wv; p < 9; p += 4) {
            const int ct = p / 3, dt = p - ct*3;
            f4 acc = {0.f, 0.f, 0.f, 0.f};
            const char* qbase = (const char*)&qk32[0][ct*16 + m][0] + quad*16;
            const char* kbase = (const char*)&qk32[1][dt*16 + m][0] + quad*16;
            #pragma unroll
            for (int ks = 0; ks < 8; ++ks) {
                short8 afr = *(const short8*)(qbase + ks*64);
                short8 bfr = *(const short8*)(kbase + ks*64);
                acc = __builtin_amdgcn_mfma_f32_16x16x32_bf16(afr, bfr, acc, 0, 0, 0);
            }
            const int c0 = ct*16 + quad*4, d = dt*16 + m;
            float* Sp = Sws + ((size_t)(b*NH + hd)*CH + c0)*CH + d;
            #pragma unroll
            for (int r = 0; r < 4; ++r) atomicAdd(Sp + r*CH, acc[r]);
        }
    }
}

// K2: one block per (b,head): norms -> logits -> softmax -> W2 = wproj*attn,
// exported bf16 in [o][dg] (A-operand-ready) layout.
__global__ __launch_bounds__(256) void k_attn(
    const float* __restrict__ Sws, const float* __restrict__ sqws,
    const float* __restrict__ temp, const float* __restrict__ wproj,
    unsigned short* __restrict__ W2bf)
{
    __shared__ float att[CH][CH+1];
    __shared__ float wp[CC][CH+1];
    __shared__ float nrm[2][CH];

    const int tid = threadIdx.x;
    const int b  = blockIdx.x >> 2;
    const int hd = blockIdx.x & 3;

    if (tid < 2*CH) {
        int which = tid / CH, cl = tid - which*CH;
        nrm[which][cl] = fmaxf(sqrtf(sqws[((b*NH + hd)*2 + which)*CH + cl]), 1e-12f);
    }
    __syncthreads();

    const float tscale = temp[hd];
    for (int m = tid; m < CH*CH; m += 256) {
        int c = m / CH, d = m - c*CH;
        att[c][d] = Sws[((size_t)(b*NH + hd)*CH + c)*CH + d] * tscale
                    / (nrm[0][c] * nrm[1][d]);
    }
    __syncthreads();

    if (tid < CH) {
        float mx = -1e30f;
        for (int d = 0; d < CH; ++d) mx = fmaxf(mx, att[tid][d]);
        float sm = 0.f;
        for (int d = 0; d < CH; ++d) { float e = expf(att[tid][d] - mx); att[tid][d] = e; sm += e; }
        float inv = 1.f / sm;
        for (int d = 0; d < CH; ++d) att[tid][d] *= inv;
    }

    for (int m = tid; m < CC*CH; m += 256) {
        int o = m / CH, il = m - o*CH;
        wp[o][il] = wproj[o*CC + hd*CH + il];
    }
    __syncthreads();

    const int o0  = (tid & 31) * 6;
    const int dl0 = (tid >> 5) * 6;
    float a[6][6];
    #pragma unroll
    for (int i = 0; i < 6; ++i)
        #pragma unroll
        for (int j = 0; j < 6; ++j) a[i][j] = 0.f;
    for (int il = 0; il < CH; ++il) {
        float wv[6], av[6];
        #pragma unroll
        for (int i = 0; i < 6; ++i) wv[i] = wp[o0+i][il];
        #pragma unroll
        for (int j = 0; j < 6; ++j) av[j] = att[il][dl0+j];
        #pragma unroll
        for (int i = 0; i < 6; ++i)
            #pragma unroll
            for (int j = 0; j < 6; ++j)
                a[i][j] = fmaf(wv[i], av[j], a[i][j]);
    }
    #pragma unroll
    for (int i = 0; i < 6; ++i)
        #pragma unroll
        for (int j = 0; j < 6; ++j)
            W2bf[((size_t)b*CC + o0 + i)*CC + hd*CH + dl0 + j] = f2bf(a[i][j]);
}

// K3: out[b][o][n] = sum_dg W2[o][dg] v[n][dg]  — MFMA GEMM.
// vs round-4: block tile M=96 x N=128 (grid carries mh = which M-half).
// W2 staging halves to 96 rows = 38400 B -> __launch_bounds__(256,4):
// 4 blocks/CU = 4 waves/SIMD (was 2). B (vws) re-read 2x but L3-resident.
// 4 waves = 1M x 4N; per wave 6 mt x 2 nt, acc 48 VGPR. Epilogue: LDS
// transpose (2 phases: 4 mt + 2 mt, 34.8 KB region) -> dwordx4 stores.
__global__ __launch_bounds__(256, 4) void k_out(
    const unsigned short* __restrict__ vws, const unsigned short* __restrict__ W2bf,
    float* __restrict__ out)
{
    __shared__ unsigned short w2l[96][200];   // 38400 B -> 4 blocks/CU

    const int tid = threadIdx.x;
    const int b   = blockIdx.y;
    const int nblk = blockIdx.x >> 1;
    const int mh   = blockIdx.x & 1;
    const int n0 = nblk * 128;
    const int m_base = mh * 96;

    {
        for (int i = tid; i < 96*24; i += 256) {
            int o = i / 24, c = i - o*24;
            *(uint4*)&w2l[o][c*8] =
                ((const uint4*)(W2bf + ((size_t)(b*CC + m_base + o))*CC))[c];
        }
    }
    __syncthreads();

    const int lane = tid & 63;
    const int wv = tid >> 6;
    const int nn0 = wv * 32;
    const int m = lane & 15, quad = lane >> 4;

    f4 acc[6][2];
    #pragma unroll
    for (int mt = 0; mt < 6; ++mt)
        #pragma unroll
        for (int nt = 0; nt < 2; ++nt) acc[mt][nt] = (f4){0.f, 0.f, 0.f, 0.f};

    const unsigned short* vb = vws + ((size_t)b*NPIX + n0 + nn0 + m)*CC + quad*8;

    #pragma unroll
    for (int ks = 0; ks < 6; ++ks) {
        short8 bfr[2];
        #pragma unroll
        for (int nt = 0; nt < 2; ++nt)
            bfr[nt] = *(const short8*)(vb + (size_t)(nt*16)*CC + ks*32);
        #pragma unroll
        for (int mt = 0; mt < 6; ++mt) {
            short8 afr = *(const short8*)&w2l[mt*16 + m][ks*32 + quad*8];
            #pragma unroll
            for (int nt = 0; nt < 2; ++nt)
                acc[mt][nt] = __builtin_amdgcn_mfma_f32_16x16x32_bf16(afr, bfr[nt], acc[mt][nt], 0, 0, 0);
        }
    }

    // ---- epilogue: per-wave LDS transpose (reuse w2l) -> dwordx4 stores.
    // region: [wave 4][mtl 4][o_local 16][px 32+2pad] f32 = 34816 B < 38400.
    float* trsp = (float*)w2l;
    const int orow = lane >> 2;          // 0..15
    const int seg  = (lane & 3) * 8;     // 0,8,16,24

    #pragma unroll
    for (int ph = 0; ph < 2; ++ph) {
        const int mtb = ph * 4;
        const int nmt = (ph == 0) ? 4 : 2;
        __syncthreads();                 // w2l/trsp reads of prev phase done
        #pragma unroll
        for (int mtl = 0; mtl < 4; ++mtl) {
            if (mtl >= nmt) break;
            #pragma unroll
            for (int nt = 0; nt < 2; ++nt)
                #pragma unroll
                for (int r = 0; r < 4; ++r)
                    trsp[((wv*4 + mtl)*16 + quad*4 + r)*34 + nt*16 + m] = acc[mtb+mtl][nt][r];
        }
        __syncthreads();
        #pragma unroll
        for (int mtl = 0; mtl < 4; ++mtl) {
            if (mtl >= nmt) break;
            const float* srcp = &trsp[((wv*4 + mtl)*16 + orow)*34 + seg];
            f4 d0 = *(const f4*)(srcp + 0);
            f4 d1 = *(const f4*)(srcp + 4);
            const int o = m_base + (mtb + mtl)*16 + orow;
            float* op = out + ((size_t)(b*CC + o))*NPIX + n0 + nn0 + seg;
            *(f4*)(op + 0) = d0;
            *(f4*)(op + 4) = d1;
        }
    }
}

extern "C" void kernel_launch(void* const* d_in, const int* in_sizes, int n_in,
                              void* d_out, int out_size, void* d_ws, size_t ws_size,
                              hipStream_t stream)
{
    const float* x     = (const float*)d_in[0];
    const float* wqkv  = (const float*)d_in[1];
    const float* temp  = (const float*)d_in[2];
    const float* wproj = (const float*)d_in[3];
    float* out = (float*)d_out;
    (void)in_sizes; (void)n_in; (void)out_size; (void)ws_size;

    unsigned short* vws = (unsigned short*)d_ws;                 // [b][n][dg] bf16: 50,331,648 B
    const size_t VBYTES = (size_t)BB*CC*NPIX*sizeof(unsigned short);
    float* Sws  = (float*)((char*)d_ws + VBYTES);                // 18432 f
    float* sqws = Sws + (size_t)BB*NH*CH*CH;                     // 768 f
    unsigned short* W2bf = (unsigned short*)(sqws + (size_t)BB*NH*2*CH); // 73728 u16

    hipMemsetAsync(Sws, 0, (size_t)(BB*NH*CH*CH + BB*NH*2*CH)*sizeof(float), stream);
    k_conv<<<dim3(NH, HH, BB), 256, 0, stream>>>(x, wqkv, vws, Sws, sqws);
    k_attn<<<dim3(BB*NH), 256, 0, stream>>>(Sws, sqws, temp, wproj, W2bf);
    k_out<<<dim3((NPIX/128)*2, BB), 256, 0, stream>>>(vws, W2bf, out);
}